// Round 24
// baseline (277.742 us; speedup 1.0000x reference)
//
#include <hip/hip_runtime.h>

#define N_ANCH 8732
#define NCLS   21
#define BATCH  128
#define TOPK   200
#define CONF_T 0.01f
#define NMS_T  0.45f
#define HSIZE  1024        // logical buckets; populated range [0, 861]
#define CAND_MAX 1024
#define NQ4    2183        // 8732 / 4 exactly

// XLA:CPU GenerateVF32Exp (classic Cephes) compiled with AllowFPOpFusion=Fast.
__device__ __forceinline__ float exp_np(float x) {
    const float fx = floorf(__fmaf_rn(x, 1.442695040888963f, 0.5f));
    float t = __fmaf_rn(fx, -0.693359375f, x);
    t = __fmaf_rn(fx, 2.12194440e-4f, t);
    const float z = __fmul_rn(t, t);
    float y = 1.9875691500e-4f;
    y = __fmaf_rn(y, t, 1.3981999507e-3f);
    y = __fmaf_rn(y, t, 8.3334519073e-3f);
    y = __fmaf_rn(y, t, 4.1665795894e-2f);
    y = __fmaf_rn(y, t, 1.6666665459e-1f);
    y = __fmaf_rn(y, t, 5.0000001201e-1f);
    y = __fmaf_rn(y, z, t);
    y = __fadd_rn(y, 1.0f);
    return ldexpf(y, (int)fx);
}

// ---------------------------------------------------------------------------
// Kernel A (verified r18): VF=16 masked-tail vectorized reduce softmax +
// FMA-fused decode. probs transposed [b][c-1][n]; boxes [b][n][4].
// ---------------------------------------------------------------------------
__global__ __launch_bounds__(256) void prep_kernel(
    const float* __restrict__ loc, const float* __restrict__ conf,
    const float* __restrict__ dbox, float* __restrict__ probs,
    float* __restrict__ boxes)
{
    __shared__ float srow[256 * NCLS];
    const int block_row0 = blockIdx.x * 256;
    const float* cbase = conf + (size_t)block_row0 * NCLS;
    for (int i = threadIdx.x; i < 256 * NCLS; i += 256) srow[i] = cbase[i];
    __syncthreads();

    const int row = block_row0 + threadIdx.x;      // grid exact: 4366*256
    const int b = row / N_ANCH;
    const int n = row - b * N_ANCH;

    float e[NCLS];
    float m = srow[threadIdx.x * NCLS];
#pragma unroll
    for (int c = 1; c < NCLS; ++c) m = fmaxf(m, srow[threadIdx.x * NCLS + c]);
#pragma unroll
    for (int c = 0; c < NCLS; ++c)
        e[c] = exp_np(__fsub_rn(srow[threadIdx.x * NCLS + c], m));

    // VF=16 masked-tail reduce (verified r18)
    float acc[16];
#pragma unroll
    for (int j = 0; j < 16; ++j) acc[j] = e[j];
#pragma unroll
    for (int j = 0; j < 5; ++j) acc[j] = __fadd_rn(acc[j], e[16 + j]);
    float u[8];
#pragma unroll
    for (int j = 0; j < 8; ++j) u[j] = __fadd_rn(acc[j], acc[j + 8]);
    const float v0 = __fadd_rn(u[0], u[4]), v1 = __fadd_rn(u[1], u[5]);
    const float v2 = __fadd_rn(u[2], u[6]), v3 = __fadd_rn(u[3], u[7]);
    const float w0 = __fadd_rn(v0, v2), w1 = __fadd_rn(v1, v3);
    const float s  = __fadd_rn(w0, w1);

#pragma unroll
    for (int c = 1; c < NCLS; ++c)
        probs[((size_t)b * 20 + (c - 1)) * N_ANCH + n] = __fdiv_rn(e[c], s);

    const float4 l = *(const float4*)(loc + (size_t)row * 4);
    const float4 d = *(const float4*)(dbox + (size_t)n * 4);
    const float cx = __fmaf_rn(__fmul_rn(l.x, 0.1f), d.z, d.x);
    const float cy = __fmaf_rn(__fmul_rn(l.y, 0.1f), d.w, d.y);
    const float w  = __fmul_rn(d.z, exp_np(__fmul_rn(l.z, 0.2f)));
    const float h  = __fmul_rn(d.w, exp_np(__fmul_rn(l.w, 0.2f)));
    const float x1 = __fmaf_rn(w, -0.5f, cx);
    const float y1 = __fmaf_rn(h, -0.5f, cy);
    float4 o; o.x = x1; o.y = y1; o.z = __fadd_rn(x1, w); o.w = __fadd_rn(y1, h);
    *(float4*)(boxes + (size_t)row * 4) = o;
}

// ---------------------------------------------------------------------------
// Kernel B (verified r22/r23): histogram top-200 + rank-sort (value desc,
// index ASC ties). Writes ordered (score,x1,y1,x2,y2) x200 into own prob row.
// ---------------------------------------------------------------------------
__global__ __launch_bounds__(256) void sel_kernel(
    const float* __restrict__ probs, const float* __restrict__ boxes,
    float* __restrict__ probs_mut)
{
    const int task = blockIdx.x;                  // b*21 + c
    const int b = task / NCLS;
    const int c = task - b * NCLS;
    const int tid = threadIdx.x;
    if (c == 0) return;                           // class 0 emitted by nms_kernel

    const float* prow = probs + ((size_t)b * 20 + (c - 1)) * N_ANCH;

    __shared__ int hist2[HSIZE * 2];
    __shared__ int wsum[4];
    __shared__ unsigned long long cand[CAND_MAX];
    __shared__ int selB;
    __shared__ int cnts[2];
    __shared__ unsigned ck[TOPK];
    __shared__ int  cn[TOPK];
    __shared__ unsigned sk[TOPK];
    __shared__ int  sn_[TOPK];

    const int wid = tid >> 6, lane = tid & 63;
    const int par = wid & 1;

    for (int i = tid; i < HSIZE * 2; i += 256) hist2[i] = 0;
    __syncthreads();
    for (int idx = tid; idx < NQ4; idx += 256) {
        const float4 v = *(const float4*)(prow + idx * 4);
        if (v.x > CONF_T) atomicAdd(&hist2[(int)((__float_as_uint(v.x) >> 16) - 0x3C23u) * 2 + par], 1);
        if (v.y > CONF_T) atomicAdd(&hist2[(int)((__float_as_uint(v.y) >> 16) - 0x3C23u) * 2 + par], 1);
        if (v.z > CONF_T) atomicAdd(&hist2[(int)((__float_as_uint(v.z) >> 16) - 0x3C23u) * 2 + par], 1);
        if (v.w > CONF_T) atomicAdd(&hist2[(int)((__float_as_uint(v.w) >> 16) - 0x3C23u) * 2 + par], 1);
    }
    __syncthreads();

    const int hbase = HSIZE - 4 * (tid + 1);
    int hb[4];
#pragma unroll
    for (int j = 0; j < 4; ++j) hb[j] = hist2[(hbase + j) * 2] + hist2[(hbase + j) * 2 + 1];
    const int part = hb[0] + hb[1] + hb[2] + hb[3];

    int incl = part;
#pragma unroll
    for (int off = 1; off < 64; off <<= 1) {
        const int v = __shfl_up(incl, off);
        if (lane >= off) incl += v;
    }
    if (lane == 63) wsum[wid] = incl;
    __syncthreads();
    int pre = 0;
    for (int w = 0; w < wid; ++w) pre += wsum[w];
    const int excl  = pre + incl - part;
    const int total = wsum[0] + wsum[1] + wsum[2] + wsum[3];
    if (tid == 0 && total < TOPK) selB = -1;
    if (excl < TOPK && excl + part >= TOPK) {
        int cacc = excl;
        for (int j = 3; j >= 0; --j) {
            if (cacc + hb[j] >= TOPK) { selB = hbase + j; break; }
            cacc += hb[j];
        }
    }
    if (tid == 0) { cnts[0] = 0; cnts[1] = 0; }
    __syncthreads();
    const int B = selB;

    for (int idx = tid; idx < NQ4; idx += 256) {
        const float4 v = *(const float4*)(prow + idx * 4);
        const float vv[4] = {v.x, v.y, v.z, v.w};
#pragma unroll
        for (int q = 0; q < 4; ++q) {
            const float s = vv[q];
            if (s > CONF_T) {
                const unsigned kk = __float_as_uint(s);
                const int bkt = (int)((kk >> 16) - 0x3C23u);
                if (bkt > B) {
                    const int p = atomicAdd(&cnts[0], 1);
                    ck[p] = kk; cn[p] = idx * 4 + q;
                } else if (bkt == B) {
                    const int qq = atomicAdd(&cnts[1], 1);
                    if (qq < CAND_MAX)
                        cand[qq] = ((unsigned long long)kk << 32) | (unsigned)(~(idx * 4 + q));
                }
            }
        }
    }
    __syncthreads();
    const int ndef  = cnts[0];
    const int slots = TOPK - ndef;
    int cc = cnts[1]; if (cc > CAND_MAX) cc = CAND_MAX;
    for (int i = tid; i < cc; i += 256) {
        const unsigned long long mine = cand[i];
        int rank = 0;
        for (int j = 0; j < cc; ++j) rank += (cand[j] > mine) ? 1 : 0;
        if (rank < slots) {
            const int p = atomicAdd(&cnts[0], 1);
            ck[p] = (unsigned)(mine >> 32);
            cn[p] = (int)(~(unsigned)mine);
        }
    }
    __syncthreads();
    const int cnt_arr = cnts[0];

    if (tid < TOPK) { sk[tid] = 0u; sn_[tid] = -1; }
    __syncthreads();
    if (tid < cnt_arr) {
        const unsigned mk = ck[tid];
        const int mn = cn[tid];
        int rank = 0;
        for (int j = 0; j < cnt_arr; ++j) {
            const unsigned kj = ck[j];
            rank += (kj > mk || (kj == mk && cn[j] < mn)) ? 1 : 0;
        }
        sk[rank] = mk; sn_[rank] = mn;
    }
    __syncthreads();

    float* selrow = probs_mut + ((size_t)b * 20 + (c - 1)) * N_ANCH;
    for (int i = tid; i < TOPK; i += 256) {
        const int n = sn_[i];
        float scv = 0.f;
        float4 bx = make_float4(0.f, 0.f, 0.f, 0.f);
        if (n >= 0) {
            scv = __uint_as_float(sk[i]);
            bx = *(const float4*)(boxes + ((size_t)b * N_ANCH + n) * 4);
        }
        float* dst = selrow + i * 5;
        dst[0] = scv; dst[1] = bx.x; dst[2] = bx.y; dst[3] = bx.z; dst[4] = bx.w;
    }
}

// ---------------------------------------------------------------------------
// Kernel C v4: bitmask NMS. One task per 256-thread block.
// Phase 1 (parallel): wave w computes suppression rows i in [50w, 50w+50):
//   rows[i][s] = ballot over lanes of (j>i && IoU(i,j)>T), j = s*64+lane.
// Phase 2 (short serial, redundant on all threads): K &= ~(rows[i] & -bit_i).
// Phase 3: dest-driven compaction (thread d emits d-th kept box or zeros).
// IoU ops bit-identical to the verified sequential version.
// ---------------------------------------------------------------------------
__global__ __launch_bounds__(256) void nms_kernel(
    const float* __restrict__ sel, float* __restrict__ out)
{
    const int task = blockIdx.x;                  // grid 2688, one task/block
    const int b = task / NCLS;
    const int c = task - b * NCLS;
    float* obase = out + (size_t)task * (TOPK * 5);
    const int tid = threadIdx.x;
    const int wv = tid >> 6, lane = tid & 63;

    if (c == 0) {
        for (int i = tid; i < TOPK * 5; i += 256) obase[i] = 0.f;
        return;
    }
    const float* srow = sel + ((size_t)b * 20 + (c - 1)) * N_ANCH;

    __shared__ float bxs[TOPK * 5];                       // 4 KB
    __shared__ unsigned long long rows[TOPK][4];          // 6.4 KB
    __shared__ unsigned long long Ksh[4];

    for (int i = tid; i < TOPK * 5; i += 256) bxs[i] = srow[i];
    __syncthreads();

    // per-lane j-boxes (slot s: j = s*64+lane)
    float jx1[4], jy1[4], jx2[4], jy2[4], jar[4];
    int jval[4];
#pragma unroll
    for (int s = 0; s < 4; ++s) {
        const int j = s * 64 + lane;
        float a = 0.f, p1 = 0.f, p2 = 0.f, p3 = 0.f, p4 = 0.f;
        if (j < TOPK) {
            a = bxs[j * 5 + 0];
            p1 = bxs[j * 5 + 1]; p2 = bxs[j * 5 + 2];
            p3 = bxs[j * 5 + 3]; p4 = bxs[j * 5 + 4];
        }
        jx1[s] = p1; jy1[s] = p2; jx2[s] = p3; jy2[s] = p4;
        jar[s] = __fmul_rn(__fsub_rn(p3, p1), __fsub_rn(p4, p2));
        jval[s] = (a > CONF_T) ? 1 : 0;
    }
    if (wv == 0) {
#pragma unroll
        for (int s = 0; s < 4; ++s) {
            const unsigned long long m = __ballot(jval[s] != 0);
            if (lane == 0) Ksh[s] = m;
        }
    }

    // ---- phase 1: suppression rows (wave w: 50 rows) ----------------------
    const int i0 = wv * 50;
    for (int i = i0; i < i0 + 50; ++i) {
        const float ix1 = bxs[i * 5 + 1], iy1 = bxs[i * 5 + 2];
        const float ix2 = bxs[i * 5 + 3], iy2 = bxs[i * 5 + 4];
        const float ia  = __fmul_rn(__fsub_rn(ix2, ix1), __fsub_rn(iy2, iy1));
#pragma unroll
        for (int s = 0; s < 4; ++s) {
            const int j = s * 64 + lane;
            const float w = fmaxf(0.f, __fsub_rn(fminf(jx2[s], ix2), fmaxf(jx1[s], ix1)));
            const float h = fmaxf(0.f, __fsub_rn(fminf(jy2[s], iy2), fmaxf(jy1[s], iy1)));
            const float inter = __fmul_rn(w, h);
            const float denom = __fadd_rn(__fsub_rn(jar[s], inter), ia);
            const float iou = __fdiv_rn(inter, denom);
            const bool bit = (j < TOPK) && (j > i) && (iou > NMS_T);
            const unsigned long long m = __ballot(bit);
            if (lane == 0) rows[i][s] = m;
        }
    }
    __syncthreads();

    // ---- phase 2: serial resolution (redundant on all threads) ------------
    unsigned long long K0 = Ksh[0], K1 = Ksh[1], K2 = Ksh[2], K3 = Ksh[3];
#pragma unroll
    for (int w4 = 0; w4 < 4; ++w4) {
        const int lim = (w4 < 3) ? 64 : (TOPK - 192);
        for (int o = 0; o < lim; ++o) {
            const int i = w4 * 64 + o;
            unsigned long long live;
            if (w4 == 0) live = (K0 >> o) & 1ull;
            else if (w4 == 1) live = (K1 >> o) & 1ull;
            else if (w4 == 2) live = (K2 >> o) & 1ull;
            else live = (K3 >> o) & 1ull;
            const unsigned long long msel = 0ull - live;
            K0 &= ~(rows[i][0] & msel);
            K1 &= ~(rows[i][1] & msel);
            K2 &= ~(rows[i][2] & msel);
            K3 &= ~(rows[i][3] & msel);
        }
    }

    // ---- phase 3: dest-driven stable compaction ---------------------------
    if (tid < TOPK) {
        const int d = tid;
        const int c0 = (int)__popcll(K0), c1 = (int)__popcll(K1),
                  c2 = (int)__popcll(K2), c3 = (int)__popcll(K3);
        const int totalk = c0 + c1 + c2 + c3;
        float o0 = 0.f, o1 = 0.f, o2 = 0.f, o3 = 0.f, o4 = 0.f;
        if (d < totalk) {
            int r = d;
            unsigned long long x;
            int wbase;
            if (r < c0)               { x = K0; wbase = 0;   }
            else if (r < c0 + c1)     { x = K1; wbase = 64;  r -= c0; }
            else if (r < c0 + c1 + c2){ x = K2; wbase = 128; r -= c0 + c1; }
            else                      { x = K3; wbase = 192; r -= c0 + c1 + c2; }
            for (int t = 0; t < r; ++t) x &= x - 1ull;       // drop r lowest set bits
            const int p = wbase + (__ffsll((unsigned long long)x) - 1);
            o0 = bxs[p * 5 + 0]; o1 = bxs[p * 5 + 1]; o2 = bxs[p * 5 + 2];
            o3 = bxs[p * 5 + 3]; o4 = bxs[p * 5 + 4];
        }
        obase[d * 5 + 0] = o0;
        obase[d * 5 + 1] = o1;
        obase[d * 5 + 2] = o2;
        obase[d * 5 + 3] = o3;
        obase[d * 5 + 4] = o4;
    }
}

extern "C" void kernel_launch(void* const* d_in, const int* in_sizes, int n_in,
                              void* d_out, int out_size, void* d_ws, size_t ws_size,
                              hipStream_t stream) {
    (void)in_sizes; (void)n_in; (void)out_size; (void)ws_size;
    const float* loc  = (const float*)d_in[0];
    const float* conf = (const float*)d_in[1];
    const float* dbox = (const float*)d_in[2];
    float* out   = (float*)d_out;
    float* probs = (float*)d_ws;                                            // 89,415,680 B
    float* boxes = (float*)((char*)d_ws + (size_t)BATCH * 20 * N_ANCH * 4); // +17,883,136 B

    prep_kernel<<<(BATCH * N_ANCH) / 256, 256, 0, stream>>>(loc, conf, dbox, probs, boxes);
    sel_kernel<<<BATCH * NCLS, 256, 0, stream>>>(probs, boxes, probs);
    nms_kernel<<<BATCH * NCLS, 256, 0, stream>>>(probs, out);
}

// Round 25
// 222.894 us; speedup vs baseline: 1.2461x; 1.2461x over previous
//
#include <hip/hip_runtime.h>

#define N_ANCH 8732
#define NCLS   21
#define BATCH  128
#define TOPK   200
#define CONF_T 0.01f
#define NMS_T  0.45f
#define HSIZE  1024        // logical buckets; populated range [0, 861]
#define CAND_MAX 1024
#define NQ4    2183        // 8732 / 4 exactly

// XLA:CPU GenerateVF32Exp (classic Cephes) compiled with AllowFPOpFusion=Fast.
__device__ __forceinline__ float exp_np(float x) {
    const float fx = floorf(__fmaf_rn(x, 1.442695040888963f, 0.5f));
    float t = __fmaf_rn(fx, -0.693359375f, x);
    t = __fmaf_rn(fx, 2.12194440e-4f, t);
    const float z = __fmul_rn(t, t);
    float y = 1.9875691500e-4f;
    y = __fmaf_rn(y, t, 1.3981999507e-3f);
    y = __fmaf_rn(y, t, 8.3334519073e-3f);
    y = __fmaf_rn(y, t, 4.1665795894e-2f);
    y = __fmaf_rn(y, t, 1.6666665459e-1f);
    y = __fmaf_rn(y, t, 5.0000001201e-1f);
    y = __fmaf_rn(y, z, t);
    y = __fadd_rn(y, 1.0f);
    return ldexpf(y, (int)fx);
}

// ---------------------------------------------------------------------------
// Kernel A (verified r18): VF=16 masked-tail vectorized reduce softmax +
// FMA-fused decode. probs transposed [b][c-1][n]; boxes [b][n][4].
// ---------------------------------------------------------------------------
__global__ __launch_bounds__(256) void prep_kernel(
    const float* __restrict__ loc, const float* __restrict__ conf,
    const float* __restrict__ dbox, float* __restrict__ probs,
    float* __restrict__ boxes)
{
    __shared__ float srow[256 * NCLS];
    const int block_row0 = blockIdx.x * 256;
    const float* cbase = conf + (size_t)block_row0 * NCLS;
    for (int i = threadIdx.x; i < 256 * NCLS; i += 256) srow[i] = cbase[i];
    __syncthreads();

    const int row = block_row0 + threadIdx.x;      // grid exact: 4366*256
    const int b = row / N_ANCH;
    const int n = row - b * N_ANCH;

    float e[NCLS];
    float m = srow[threadIdx.x * NCLS];
#pragma unroll
    for (int c = 1; c < NCLS; ++c) m = fmaxf(m, srow[threadIdx.x * NCLS + c]);
#pragma unroll
    for (int c = 0; c < NCLS; ++c)
        e[c] = exp_np(__fsub_rn(srow[threadIdx.x * NCLS + c], m));

    // VF=16 masked-tail reduce (verified r18)
    float acc[16];
#pragma unroll
    for (int j = 0; j < 16; ++j) acc[j] = e[j];
#pragma unroll
    for (int j = 0; j < 5; ++j) acc[j] = __fadd_rn(acc[j], e[16 + j]);
    float u[8];
#pragma unroll
    for (int j = 0; j < 8; ++j) u[j] = __fadd_rn(acc[j], acc[j + 8]);
    const float v0 = __fadd_rn(u[0], u[4]), v1 = __fadd_rn(u[1], u[5]);
    const float v2 = __fadd_rn(u[2], u[6]), v3 = __fadd_rn(u[3], u[7]);
    const float w0 = __fadd_rn(v0, v2), w1 = __fadd_rn(v1, v3);
    const float s  = __fadd_rn(w0, w1);

#pragma unroll
    for (int c = 1; c < NCLS; ++c)
        probs[((size_t)b * 20 + (c - 1)) * N_ANCH + n] = __fdiv_rn(e[c], s);

    const float4 l = *(const float4*)(loc + (size_t)row * 4);
    const float4 d = *(const float4*)(dbox + (size_t)n * 4);
    const float cx = __fmaf_rn(__fmul_rn(l.x, 0.1f), d.z, d.x);
    const float cy = __fmaf_rn(__fmul_rn(l.y, 0.1f), d.w, d.y);
    const float w  = __fmul_rn(d.z, exp_np(__fmul_rn(l.z, 0.2f)));
    const float h  = __fmul_rn(d.w, exp_np(__fmul_rn(l.w, 0.2f)));
    const float x1 = __fmaf_rn(w, -0.5f, cx);
    const float y1 = __fmaf_rn(h, -0.5f, cy);
    float4 o; o.x = x1; o.y = y1; o.z = __fadd_rn(x1, w); o.w = __fadd_rn(y1, h);
    *(float4*)(boxes + (size_t)row * 4) = o;
}

// ---------------------------------------------------------------------------
// Kernel B (verified r22/r23): histogram top-200 + rank-sort (value desc,
// index ASC ties). Writes ordered (score,x1,y1,x2,y2) x200 into own prob row.
// ---------------------------------------------------------------------------
__global__ __launch_bounds__(256) void sel_kernel(
    const float* __restrict__ probs, const float* __restrict__ boxes,
    float* __restrict__ probs_mut)
{
    const int task = blockIdx.x;                  // b*21 + c
    const int b = task / NCLS;
    const int c = task - b * NCLS;
    const int tid = threadIdx.x;
    if (c == 0) return;                           // class 0 emitted by nms_kernel

    const float* prow = probs + ((size_t)b * 20 + (c - 1)) * N_ANCH;

    __shared__ int hist2[HSIZE * 2];
    __shared__ int wsum[4];
    __shared__ unsigned long long cand[CAND_MAX];
    __shared__ int selB;
    __shared__ int cnts[2];
    __shared__ unsigned ck[TOPK];
    __shared__ int  cn[TOPK];
    __shared__ unsigned sk[TOPK];
    __shared__ int  sn_[TOPK];

    const int wid = tid >> 6, lane = tid & 63;
    const int par = wid & 1;

    for (int i = tid; i < HSIZE * 2; i += 256) hist2[i] = 0;
    __syncthreads();
    for (int idx = tid; idx < NQ4; idx += 256) {
        const float4 v = *(const float4*)(prow + idx * 4);
        if (v.x > CONF_T) atomicAdd(&hist2[(int)((__float_as_uint(v.x) >> 16) - 0x3C23u) * 2 + par], 1);
        if (v.y > CONF_T) atomicAdd(&hist2[(int)((__float_as_uint(v.y) >> 16) - 0x3C23u) * 2 + par], 1);
        if (v.z > CONF_T) atomicAdd(&hist2[(int)((__float_as_uint(v.z) >> 16) - 0x3C23u) * 2 + par], 1);
        if (v.w > CONF_T) atomicAdd(&hist2[(int)((__float_as_uint(v.w) >> 16) - 0x3C23u) * 2 + par], 1);
    }
    __syncthreads();

    const int hbase = HSIZE - 4 * (tid + 1);
    int hb[4];
#pragma unroll
    for (int j = 0; j < 4; ++j) hb[j] = hist2[(hbase + j) * 2] + hist2[(hbase + j) * 2 + 1];
    const int part = hb[0] + hb[1] + hb[2] + hb[3];

    int incl = part;
#pragma unroll
    for (int off = 1; off < 64; off <<= 1) {
        const int v = __shfl_up(incl, off);
        if (lane >= off) incl += v;
    }
    if (lane == 63) wsum[wid] = incl;
    __syncthreads();
    int pre = 0;
    for (int w = 0; w < wid; ++w) pre += wsum[w];
    const int excl  = pre + incl - part;
    const int total = wsum[0] + wsum[1] + wsum[2] + wsum[3];
    if (tid == 0 && total < TOPK) selB = -1;
    if (excl < TOPK && excl + part >= TOPK) {
        int cacc = excl;
        for (int j = 3; j >= 0; --j) {
            if (cacc + hb[j] >= TOPK) { selB = hbase + j; break; }
            cacc += hb[j];
        }
    }
    if (tid == 0) { cnts[0] = 0; cnts[1] = 0; }
    __syncthreads();
    const int B = selB;

    for (int idx = tid; idx < NQ4; idx += 256) {
        const float4 v = *(const float4*)(prow + idx * 4);
        const float vv[4] = {v.x, v.y, v.z, v.w};
#pragma unroll
        for (int q = 0; q < 4; ++q) {
            const float s = vv[q];
            if (s > CONF_T) {
                const unsigned kk = __float_as_uint(s);
                const int bkt = (int)((kk >> 16) - 0x3C23u);
                if (bkt > B) {
                    const int p = atomicAdd(&cnts[0], 1);
                    ck[p] = kk; cn[p] = idx * 4 + q;
                } else if (bkt == B) {
                    const int qq = atomicAdd(&cnts[1], 1);
                    if (qq < CAND_MAX)
                        cand[qq] = ((unsigned long long)kk << 32) | (unsigned)(~(idx * 4 + q));
                }
            }
        }
    }
    __syncthreads();
    const int ndef  = cnts[0];
    const int slots = TOPK - ndef;
    int cc = cnts[1]; if (cc > CAND_MAX) cc = CAND_MAX;
    for (int i = tid; i < cc; i += 256) {
        const unsigned long long mine = cand[i];
        int rank = 0;
        for (int j = 0; j < cc; ++j) rank += (cand[j] > mine) ? 1 : 0;
        if (rank < slots) {
            const int p = atomicAdd(&cnts[0], 1);
            ck[p] = (unsigned)(mine >> 32);
            cn[p] = (int)(~(unsigned)mine);
        }
    }
    __syncthreads();
    const int cnt_arr = cnts[0];

    if (tid < TOPK) { sk[tid] = 0u; sn_[tid] = -1; }
    __syncthreads();
    if (tid < cnt_arr) {
        const unsigned mk = ck[tid];
        const int mn = cn[tid];
        int rank = 0;
        for (int j = 0; j < cnt_arr; ++j) {
            const unsigned kj = ck[j];
            rank += (kj > mk || (kj == mk && cn[j] < mn)) ? 1 : 0;
        }
        sk[rank] = mk; sn_[rank] = mn;
    }
    __syncthreads();

    float* selrow = probs_mut + ((size_t)b * 20 + (c - 1)) * N_ANCH;
    for (int i = tid; i < TOPK; i += 256) {
        const int n = sn_[i];
        float scv = 0.f;
        float4 bx = make_float4(0.f, 0.f, 0.f, 0.f);
        if (n >= 0) {
            scv = __uint_as_float(sk[i]);
            bx = *(const float4*)(boxes + ((size_t)b * N_ANCH + n) * 4);
        }
        float* dst = selrow + i * 5;
        dst[0] = scv; dst[1] = bx.x; dst[2] = bx.y; dst[3] = bx.z; dst[4] = bx.w;
    }
}

// ---------------------------------------------------------------------------
// Kernel C v5: lean bitmask NMS. One task per 256-thread block.
// Phase 1: interleaved rows (i = wv mod 4), TRIANGLE slots only (s >= i>>6).
// Phase 2: wave 0 only — 200 cheap bit-iterations (K-independent LDS loads
// pipeline; chain ~5K cycles). Phase 3: dest-driven compaction (r24, ✓).
// IoU ops bit-identical to verified versions.
// ---------------------------------------------------------------------------
__global__ __launch_bounds__(256) void nms_kernel(
    const float* __restrict__ sel, float* __restrict__ out)
{
    const int task = blockIdx.x;                  // grid 2688, one task/block
    const int b = task / NCLS;
    const int c = task - b * NCLS;
    float* obase = out + (size_t)task * (TOPK * 5);
    const int tid = threadIdx.x;
    const int wv = tid >> 6, lane = tid & 63;

    if (c == 0) {
        for (int i = tid; i < TOPK * 5; i += 256) obase[i] = 0.f;
        return;
    }
    const float* srow = sel + ((size_t)b * 20 + (c - 1)) * N_ANCH;

    __shared__ float bxs[TOPK * 5];                       // 4 KB
    __shared__ unsigned long long rows[TOPK][4];          // 6.4 KB
    __shared__ unsigned long long Ksh[4];

    for (int i = tid; i < TOPK * 5; i += 256) bxs[i] = srow[i];
    __syncthreads();

    // per-lane j-boxes (slot s: j = s*64+lane)
    float jx1[4], jy1[4], jx2[4], jy2[4], jar[4];
    int jval[4];
#pragma unroll
    for (int s = 0; s < 4; ++s) {
        const int j = s * 64 + lane;
        float a = 0.f, p1 = 0.f, p2 = 0.f, p3 = 0.f, p4 = 0.f;
        if (j < TOPK) {
            a = bxs[j * 5 + 0];
            p1 = bxs[j * 5 + 1]; p2 = bxs[j * 5 + 2];
            p3 = bxs[j * 5 + 3]; p4 = bxs[j * 5 + 4];
        }
        jx1[s] = p1; jy1[s] = p2; jx2[s] = p3; jy2[s] = p4;
        jar[s] = __fmul_rn(__fsub_rn(p3, p1), __fsub_rn(p4, p2));
        jval[s] = (a > CONF_T) ? 1 : 0;
    }
    if (wv == 0) {
#pragma unroll
        for (int s = 0; s < 4; ++s) {
            const unsigned long long m = __ballot(jval[s] != 0);
            if (lane == 0) Ksh[s] = m;
        }
    }

    // ---- phase 1: suppression rows, interleaved + triangle ----------------
    for (int i = wv; i < TOPK; i += 4) {
        const int smin = i >> 6;
        const float ix1 = bxs[i * 5 + 1], iy1 = bxs[i * 5 + 2];
        const float ix2 = bxs[i * 5 + 3], iy2 = bxs[i * 5 + 4];
        const float ia  = __fmul_rn(__fsub_rn(ix2, ix1), __fsub_rn(iy2, iy1));
#pragma unroll
        for (int s = 0; s < 4; ++s) {
            if (s < smin) {
                if (lane == 0) rows[i][s] = 0ull;
            } else {
                const int j = s * 64 + lane;
                const float w = fmaxf(0.f, __fsub_rn(fminf(jx2[s], ix2), fmaxf(jx1[s], ix1)));
                const float h = fmaxf(0.f, __fsub_rn(fminf(jy2[s], iy2), fmaxf(jy1[s], iy1)));
                const float inter = __fmul_rn(w, h);
                const float denom = __fadd_rn(__fsub_rn(jar[s], inter), ia);
                const float iou = __fdiv_rn(inter, denom);
                const bool bit = (j < TOPK) && (j > i) && (iou > NMS_T);
                const unsigned long long m = __ballot(bit);
                if (lane == 0) rows[i][s] = m;
            }
        }
    }
    __syncthreads();

    // ---- phase 2: serial resolution on wave 0 only ------------------------
    if (wv == 0) {
        unsigned long long K0 = Ksh[0], K1 = Ksh[1], K2 = Ksh[2], K3 = Ksh[3];
#pragma unroll
        for (int w4 = 0; w4 < 4; ++w4) {
            const int lim = (w4 < 3) ? 64 : (TOPK - 192);
            for (int o = 0; o < lim; ++o) {
                const int i = w4 * 64 + o;
                const unsigned long long r0 = rows[i][0], r1 = rows[i][1];
                const unsigned long long r2 = rows[i][2], r3 = rows[i][3];
                if ((r0 | r1 | r2 | r3) == 0ull) continue;   // no suppression
                unsigned long long live;
                if (w4 == 0) live = (K0 >> o) & 1ull;
                else if (w4 == 1) live = (K1 >> o) & 1ull;
                else if (w4 == 2) live = (K2 >> o) & 1ull;
                else live = (K3 >> o) & 1ull;
                const unsigned long long msel = 0ull - live;
                K0 &= ~(r0 & msel);
                K1 &= ~(r1 & msel);
                K2 &= ~(r2 & msel);
                K3 &= ~(r3 & msel);
            }
        }
        if (lane == 0) { Ksh[0] = K0; Ksh[1] = K1; Ksh[2] = K2; Ksh[3] = K3; }
    }
    __syncthreads();

    // ---- phase 3: dest-driven stable compaction ---------------------------
    if (tid < TOPK) {
        const unsigned long long K0 = Ksh[0], K1 = Ksh[1], K2 = Ksh[2], K3 = Ksh[3];
        const int d = tid;
        const int c0 = (int)__popcll(K0), c1 = (int)__popcll(K1),
                  c2 = (int)__popcll(K2), c3 = (int)__popcll(K3);
        const int totalk = c0 + c1 + c2 + c3;
        float o0 = 0.f, o1 = 0.f, o2 = 0.f, o3 = 0.f, o4 = 0.f;
        if (d < totalk) {
            int r = d;
            unsigned long long x;
            int wbase;
            if (r < c0)               { x = K0; wbase = 0;   }
            else if (r < c0 + c1)     { x = K1; wbase = 64;  r -= c0; }
            else if (r < c0 + c1 + c2){ x = K2; wbase = 128; r -= c0 + c1; }
            else                      { x = K3; wbase = 192; r -= c0 + c1 + c2; }
            for (int t = 0; t < r; ++t) x &= x - 1ull;       // drop r lowest set bits
            const int p = wbase + (__ffsll((unsigned long long)x) - 1);
            o0 = bxs[p * 5 + 0]; o1 = bxs[p * 5 + 1]; o2 = bxs[p * 5 + 2];
            o3 = bxs[p * 5 + 3]; o4 = bxs[p * 5 + 4];
        }
        obase[d * 5 + 0] = o0;
        obase[d * 5 + 1] = o1;
        obase[d * 5 + 2] = o2;
        obase[d * 5 + 3] = o3;
        obase[d * 5 + 4] = o4;
    }
}

extern "C" void kernel_launch(void* const* d_in, const int* in_sizes, int n_in,
                              void* d_out, int out_size, void* d_ws, size_t ws_size,
                              hipStream_t stream) {
    (void)in_sizes; (void)n_in; (void)out_size; (void)ws_size;
    const float* loc  = (const float*)d_in[0];
    const float* conf = (const float*)d_in[1];
    const float* dbox = (const float*)d_in[2];
    float* out   = (float*)d_out;
    float* probs = (float*)d_ws;                                            // 89,415,680 B
    float* boxes = (float*)((char*)d_ws + (size_t)BATCH * 20 * N_ANCH * 4); // +17,883,136 B

    prep_kernel<<<(BATCH * N_ANCH) / 256, 256, 0, stream>>>(loc, conf, dbox, probs, boxes);
    sel_kernel<<<BATCH * NCLS, 256, 0, stream>>>(probs, boxes, probs);
    nms_kernel<<<BATCH * NCLS, 256, 0, stream>>>(probs, out);
}

// Round 26
// 210.922 us; speedup vs baseline: 1.3168x; 1.0568x over previous
//
#include <hip/hip_runtime.h>

#define N_ANCH 8732
#define NCLS   21
#define BATCH  128
#define TOPK   200
#define CONF_T 0.01f
#define HSIZE  1024        // logical buckets; populated range [0, 861]
#define CAND_MAX 1024
#define NQ4    2183        // 8732 / 4 exactly

// Exact div-free NMS threshold: RN(inter/denom) > 0.45f  <=>  inter > MD*denom
// (MD = midpoint(0.45f, nextafterf(0.45f)); tie rounds to even = 0.45f).
// MD has 25 bits, denom 24 -> MD*denom exact in double -> comparison exact.
#define MD 0x1.CCCCCDp-2

// XLA:CPU GenerateVF32Exp (classic Cephes) compiled with AllowFPOpFusion=Fast.
__device__ __forceinline__ float exp_np(float x) {
    const float fx = floorf(__fmaf_rn(x, 1.442695040888963f, 0.5f));
    float t = __fmaf_rn(fx, -0.693359375f, x);
    t = __fmaf_rn(fx, 2.12194440e-4f, t);
    const float z = __fmul_rn(t, t);
    float y = 1.9875691500e-4f;
    y = __fmaf_rn(y, t, 1.3981999507e-3f);
    y = __fmaf_rn(y, t, 8.3334519073e-3f);
    y = __fmaf_rn(y, t, 4.1665795894e-2f);
    y = __fmaf_rn(y, t, 1.6666665459e-1f);
    y = __fmaf_rn(y, t, 5.0000001201e-1f);
    y = __fmaf_rn(y, z, t);
    y = __fadd_rn(y, 1.0f);
    return ldexpf(y, (int)fx);
}

// ---------------------------------------------------------------------------
// Kernel A (verified r18): VF=16 masked-tail vectorized reduce softmax +
// FMA-fused decode. probs transposed [b][c-1][n]; boxes [b][n][4].
// ---------------------------------------------------------------------------
__global__ __launch_bounds__(256) void prep_kernel(
    const float* __restrict__ loc, const float* __restrict__ conf,
    const float* __restrict__ dbox, float* __restrict__ probs,
    float* __restrict__ boxes)
{
    __shared__ float srow[256 * NCLS];
    const int block_row0 = blockIdx.x * 256;
    const float* cbase = conf + (size_t)block_row0 * NCLS;
    for (int i = threadIdx.x; i < 256 * NCLS; i += 256) srow[i] = cbase[i];
    __syncthreads();

    const int row = block_row0 + threadIdx.x;      // grid exact: 4366*256
    const int b = row / N_ANCH;
    const int n = row - b * N_ANCH;

    float e[NCLS];
    float m = srow[threadIdx.x * NCLS];
#pragma unroll
    for (int c = 1; c < NCLS; ++c) m = fmaxf(m, srow[threadIdx.x * NCLS + c]);
#pragma unroll
    for (int c = 0; c < NCLS; ++c)
        e[c] = exp_np(__fsub_rn(srow[threadIdx.x * NCLS + c], m));

    // VF=16 masked-tail reduce (verified r18)
    float acc[16];
#pragma unroll
    for (int j = 0; j < 16; ++j) acc[j] = e[j];
#pragma unroll
    for (int j = 0; j < 5; ++j) acc[j] = __fadd_rn(acc[j], e[16 + j]);
    float u[8];
#pragma unroll
    for (int j = 0; j < 8; ++j) u[j] = __fadd_rn(acc[j], acc[j + 8]);
    const float v0 = __fadd_rn(u[0], u[4]), v1 = __fadd_rn(u[1], u[5]);
    const float v2 = __fadd_rn(u[2], u[6]), v3 = __fadd_rn(u[3], u[7]);
    const float w0 = __fadd_rn(v0, v2), w1 = __fadd_rn(v1, v3);
    const float s  = __fadd_rn(w0, w1);

#pragma unroll
    for (int c = 1; c < NCLS; ++c)
        probs[((size_t)b * 20 + (c - 1)) * N_ANCH + n] = __fdiv_rn(e[c], s);

    const float4 l = *(const float4*)(loc + (size_t)row * 4);
    const float4 d = *(const float4*)(dbox + (size_t)n * 4);
    const float cx = __fmaf_rn(__fmul_rn(l.x, 0.1f), d.z, d.x);
    const float cy = __fmaf_rn(__fmul_rn(l.y, 0.1f), d.w, d.y);
    const float w  = __fmul_rn(d.z, exp_np(__fmul_rn(l.z, 0.2f)));
    const float h  = __fmul_rn(d.w, exp_np(__fmul_rn(l.w, 0.2f)));
    const float x1 = __fmaf_rn(w, -0.5f, cx);
    const float y1 = __fmaf_rn(h, -0.5f, cy);
    float4 o; o.x = x1; o.y = y1; o.z = __fadd_rn(x1, w); o.w = __fadd_rn(y1, h);
    *(float4*)(boxes + (size_t)row * 4) = o;
}

// ---------------------------------------------------------------------------
// Kernel B: histogram top-200 + rank-sort (value desc, index ASC ties).
// Boundary bucket now refined with a level-2 8-bit histogram so the exact
// rank-select runs only on a tiny tie group (selected SET provably same).
// Writes ordered (score,x1,y1,x2,y2) x200 into own prob row.
// ---------------------------------------------------------------------------
__global__ __launch_bounds__(256) void sel_kernel(
    const float* __restrict__ probs, const float* __restrict__ boxes,
    float* __restrict__ probs_mut)
{
    const int task = blockIdx.x;                  // b*21 + c
    const int b = task / NCLS;
    const int c = task - b * NCLS;
    const int tid = threadIdx.x;
    if (c == 0) return;                           // class 0 emitted by nms_kernel

    const float* prow = probs + ((size_t)b * 20 + (c - 1)) * N_ANCH;

    __shared__ int hist2[HSIZE * 2];
    __shared__ int wsum[4];
    __shared__ unsigned long long cand[CAND_MAX];
    __shared__ int selB;
    __shared__ int cnts[2];
    __shared__ unsigned ck[TOPK];
    __shared__ int  cn[TOPK];
    __shared__ unsigned sk[TOPK];
    __shared__ int  sn_[TOPK];

    const int wid = tid >> 6, lane = tid & 63;
    const int par = wid & 1;

    for (int i = tid; i < HSIZE * 2; i += 256) hist2[i] = 0;
    __syncthreads();
    for (int idx = tid; idx < NQ4; idx += 256) {
        const float4 v = *(const float4*)(prow + idx * 4);
        if (v.x > CONF_T) atomicAdd(&hist2[(int)((__float_as_uint(v.x) >> 16) - 0x3C23u) * 2 + par], 1);
        if (v.y > CONF_T) atomicAdd(&hist2[(int)((__float_as_uint(v.y) >> 16) - 0x3C23u) * 2 + par], 1);
        if (v.z > CONF_T) atomicAdd(&hist2[(int)((__float_as_uint(v.z) >> 16) - 0x3C23u) * 2 + par], 1);
        if (v.w > CONF_T) atomicAdd(&hist2[(int)((__float_as_uint(v.w) >> 16) - 0x3C23u) * 2 + par], 1);
    }
    __syncthreads();

    const int hbase = HSIZE - 4 * (tid + 1);
    int hb[4];
#pragma unroll
    for (int j = 0; j < 4; ++j) hb[j] = hist2[(hbase + j) * 2] + hist2[(hbase + j) * 2 + 1];
    const int part = hb[0] + hb[1] + hb[2] + hb[3];

    int incl = part;
#pragma unroll
    for (int off = 1; off < 64; off <<= 1) {
        const int v = __shfl_up(incl, off);
        if (lane >= off) incl += v;
    }
    if (lane == 63) wsum[wid] = incl;
    __syncthreads();
    int pre = 0;
    for (int w = 0; w < wid; ++w) pre += wsum[w];
    const int excl  = pre + incl - part;
    const int total = wsum[0] + wsum[1] + wsum[2] + wsum[3];
    if (tid == 0 && total < TOPK) selB = -1;
    if (excl < TOPK && excl + part >= TOPK) {
        int cacc = excl;
        for (int j = 3; j >= 0; --j) {
            if (cacc + hb[j] >= TOPK) { selB = hbase + j; break; }
            cacc += hb[j];
        }
    }
    if (tid == 0) { cnts[0] = 0; cnts[1] = 0; }
    __syncthreads();
    const int B = selB;

    for (int idx = tid; idx < NQ4; idx += 256) {
        const float4 v = *(const float4*)(prow + idx * 4);
        const float vv[4] = {v.x, v.y, v.z, v.w};
#pragma unroll
        for (int q = 0; q < 4; ++q) {
            const float s = vv[q];
            if (s > CONF_T) {
                const unsigned kk = __float_as_uint(s);
                const int bkt = (int)((kk >> 16) - 0x3C23u);
                if (bkt > B) {
                    const int p = atomicAdd(&cnts[0], 1);
                    ck[p] = kk; cn[p] = idx * 4 + q;
                } else if (bkt == B) {
                    const int qq = atomicAdd(&cnts[1], 1);
                    if (qq < CAND_MAX)
                        cand[qq] = ((unsigned long long)kk << 32) | (unsigned)(~(idx * 4 + q));
                }
            }
        }
    }
    __syncthreads();
    const int ndef  = cnts[0];
    const int slots = TOPK - ndef;
    int cc = cnts[1]; if (cc > CAND_MAX) cc = CAND_MAX;

    if (cc <= slots) {
        // all candidates selected
        for (int i = tid; i < cc; i += 256) {
            const unsigned long long mine = cand[i];
            const int p = atomicAdd(&cnts[0], 1);
            ck[p] = (unsigned)(mine >> 32);
            cn[p] = (int)(~(unsigned)mine);
        }
        __syncthreads();
    } else {
        // ---- level-2 refinement on key bits 8..15 -------------------------
        for (int i = tid; i < 256; i += 256) hist2[i] = 0;
        __syncthreads();
        for (int i = tid; i < cc; i += 256)
            atomicAdd(&hist2[(int)((cand[i] >> 40) & 0xFFull)], 1);
        __syncthreads();
        const int sb = 255 - tid;                  // tid 0 owns highest sub-bucket
        const int part2 = hist2[sb];
        int incl2 = part2;
#pragma unroll
        for (int off = 1; off < 64; off <<= 1) {
            const int v = __shfl_up(incl2, off);
            if (lane >= off) incl2 += v;
        }
        if (lane == 63) wsum[wid] = incl2;
        __syncthreads();
        int pre2 = 0;
        for (int w = 0; w < wid; ++w) pre2 += wsum[w];
        const int excl2 = pre2 + incl2 - part2;    // candidates with subkey > mine
        if (excl2 < slots && excl2 + part2 >= slots) selB = sb;   // unique crossing
        __syncthreads();
        const int B2 = selB;
        // definites: subkey > B2 (count = excl2@crossing < slots)
        for (int i = tid; i < cc; i += 256) {
            const unsigned long long mine = cand[i];
            if ((int)((mine >> 40) & 0xFFull) > B2) {
                const int p = atomicAdd(&cnts[0], 1);
                ck[p] = (unsigned)(mine >> 32);
                cn[p] = (int)(~(unsigned)mine);
            }
        }
        __syncthreads();
        const int slots2 = TOPK - cnts[0];         // remaining from tie group
        // tie group: subkey == B2; exact rank by packed (key desc, idx asc)
        for (int i = tid; i < cc; i += 256) {
            const unsigned long long mine = cand[i];
            if ((int)((mine >> 40) & 0xFFull) == B2) {
                int rank = 0;
                for (int j = 0; j < cc; ++j) {
                    const unsigned long long oth = cand[j];
                    rank += (((int)((oth >> 40) & 0xFFull) == B2) && oth > mine) ? 1 : 0;
                }
                if (rank < slots2) {
                    const int p = atomicAdd(&cnts[0], 1);
                    ck[p] = (unsigned)(mine >> 32);
                    cn[p] = (int)(~(unsigned)mine);
                }
            }
        }
        __syncthreads();
    }
    const int cnt_arr = cnts[0];

    if (tid < TOPK) { sk[tid] = 0u; sn_[tid] = -1; }
    __syncthreads();
    if (tid < cnt_arr) {
        const unsigned mk = ck[tid];
        const int mn = cn[tid];
        int rank = 0;
        for (int j = 0; j < cnt_arr; ++j) {
            const unsigned kj = ck[j];
            rank += (kj > mk || (kj == mk && cn[j] < mn)) ? 1 : 0;
        }
        sk[rank] = mk; sn_[rank] = mn;
    }
    __syncthreads();

    float* selrow = probs_mut + ((size_t)b * 20 + (c - 1)) * N_ANCH;
    for (int i = tid; i < TOPK; i += 256) {
        const int n = sn_[i];
        float scv = 0.f;
        float4 bx = make_float4(0.f, 0.f, 0.f, 0.f);
        if (n >= 0) {
            scv = __uint_as_float(sk[i]);
            bx = *(const float4*)(boxes + ((size_t)b * N_ANCH + n) * 4);
        }
        float* dst = selrow + i * 5;
        dst[0] = scv; dst[1] = bx.x; dst[2] = bx.y; dst[3] = bx.z; dst[4] = bx.w;
    }
}

// ---------------------------------------------------------------------------
// Kernel C v6: lean bitmask NMS with exact div-free IoU test.
// Phase 1: interleaved rows, triangle slots. Phase 2: wave 0, b128 row loads.
// Phase 3: dest-driven compaction. Decisions bit-identical to verified div.
// ---------------------------------------------------------------------------
__global__ __launch_bounds__(256) void nms_kernel(
    const float* __restrict__ sel, float* __restrict__ out)
{
    const int task = blockIdx.x;                  // grid 2688, one task/block
    const int b = task / NCLS;
    const int c = task - b * NCLS;
    float* obase = out + (size_t)task * (TOPK * 5);
    const int tid = threadIdx.x;
    const int wv = tid >> 6, lane = tid & 63;

    if (c == 0) {
        for (int i = tid; i < TOPK * 5; i += 256) obase[i] = 0.f;
        return;
    }
    const float* srow = sel + ((size_t)b * 20 + (c - 1)) * N_ANCH;

    __shared__ float bxs[TOPK * 5];                       // 4 KB
    __shared__ __align__(16) unsigned long long rows[TOPK][4];  // 6.4 KB
    __shared__ unsigned long long Ksh[4];

    for (int i = tid; i < TOPK * 5; i += 256) bxs[i] = srow[i];
    __syncthreads();

    // per-lane j-boxes (slot s: j = s*64+lane)
    float jx1[4], jy1[4], jx2[4], jy2[4], jar[4];
    int jval[4];
#pragma unroll
    for (int s = 0; s < 4; ++s) {
        const int j = s * 64 + lane;
        float a = 0.f, p1 = 0.f, p2 = 0.f, p3 = 0.f, p4 = 0.f;
        if (j < TOPK) {
            a = bxs[j * 5 + 0];
            p1 = bxs[j * 5 + 1]; p2 = bxs[j * 5 + 2];
            p3 = bxs[j * 5 + 3]; p4 = bxs[j * 5 + 4];
        }
        jx1[s] = p1; jy1[s] = p2; jx2[s] = p3; jy2[s] = p4;
        jar[s] = __fmul_rn(__fsub_rn(p3, p1), __fsub_rn(p4, p2));
        jval[s] = (a > CONF_T) ? 1 : 0;
    }
    if (wv == 0) {
#pragma unroll
        for (int s = 0; s < 4; ++s) {
            const unsigned long long m = __ballot(jval[s] != 0);
            if (lane == 0) Ksh[s] = m;
        }
    }

    // ---- phase 1: suppression rows, interleaved + triangle ----------------
    for (int i = wv; i < TOPK; i += 4) {
        const int smin = i >> 6;
        const float ix1 = bxs[i * 5 + 1], iy1 = bxs[i * 5 + 2];
        const float ix2 = bxs[i * 5 + 3], iy2 = bxs[i * 5 + 4];
        const float ia  = __fmul_rn(__fsub_rn(ix2, ix1), __fsub_rn(iy2, iy1));
#pragma unroll
        for (int s = 0; s < 4; ++s) {
            if (s < smin) {
                if (lane == 0) rows[i][s] = 0ull;
            } else {
                const int j = s * 64 + lane;
                const float w = fmaxf(0.f, __fsub_rn(fminf(jx2[s], ix2), fmaxf(jx1[s], ix1)));
                const float h = fmaxf(0.f, __fsub_rn(fminf(jy2[s], iy2), fmaxf(jy1[s], iy1)));
                const float inter = __fmul_rn(w, h);
                const float denom = __fadd_rn(__fsub_rn(jar[s], inter), ia);
                // exact: RN(inter/denom) > 0.45f  <=>  inter > MD*denom
                const bool bit = (j < TOPK) && (j > i) &&
                                 ((double)inter > MD * (double)denom);
                const unsigned long long m = __ballot(bit);
                if (lane == 0) rows[i][s] = m;
            }
        }
    }
    __syncthreads();

    // ---- phase 2: serial resolution on wave 0 only ------------------------
    if (wv == 0) {
        unsigned long long K0 = Ksh[0], K1 = Ksh[1], K2 = Ksh[2], K3 = Ksh[3];
#pragma unroll
        for (int w4 = 0; w4 < 4; ++w4) {
            const int lim = (w4 < 3) ? 64 : (TOPK - 192);
            for (int o = 0; o < lim; ++o) {
                const int i = w4 * 64 + o;
                const ulonglong2 ra = *(const ulonglong2*)&rows[i][0];
                const ulonglong2 rb = *(const ulonglong2*)&rows[i][2];
                if ((ra.x | ra.y | rb.x | rb.y) == 0ull) continue;
                unsigned long long live;
                if (w4 == 0) live = (K0 >> o) & 1ull;
                else if (w4 == 1) live = (K1 >> o) & 1ull;
                else if (w4 == 2) live = (K2 >> o) & 1ull;
                else live = (K3 >> o) & 1ull;
                const unsigned long long msel = 0ull - live;
                K0 &= ~(ra.x & msel);
                K1 &= ~(ra.y & msel);
                K2 &= ~(rb.x & msel);
                K3 &= ~(rb.y & msel);
            }
        }
        if (lane == 0) { Ksh[0] = K0; Ksh[1] = K1; Ksh[2] = K2; Ksh[3] = K3; }
    }
    __syncthreads();

    // ---- phase 3: dest-driven stable compaction ---------------------------
    if (tid < TOPK) {
        const unsigned long long K0 = Ksh[0], K1 = Ksh[1], K2 = Ksh[2], K3 = Ksh[3];
        const int d = tid;
        const int c0 = (int)__popcll(K0), c1 = (int)__popcll(K1),
                  c2 = (int)__popcll(K2), c3 = (int)__popcll(K3);
        const int totalk = c0 + c1 + c2 + c3;
        float o0 = 0.f, o1 = 0.f, o2 = 0.f, o3 = 0.f, o4 = 0.f;
        if (d < totalk) {
            int r = d;
            unsigned long long x;
            int wbase;
            if (r < c0)               { x = K0; wbase = 0;   }
            else if (r < c0 + c1)     { x = K1; wbase = 64;  r -= c0; }
            else if (r < c0 + c1 + c2){ x = K2; wbase = 128; r -= c0 + c1; }
            else                      { x = K3; wbase = 192; r -= c0 + c1 + c2; }
            for (int t = 0; t < r; ++t) x &= x - 1ull;       // drop r lowest set bits
            const int p = wbase + (__ffsll((unsigned long long)x) - 1);
            o0 = bxs[p * 5 + 0]; o1 = bxs[p * 5 + 1]; o2 = bxs[p * 5 + 2];
            o3 = bxs[p * 5 + 3]; o4 = bxs[p * 5 + 4];
        }
        obase[d * 5 + 0] = o0;
        obase[d * 5 + 1] = o1;
        obase[d * 5 + 2] = o2;
        obase[d * 5 + 3] = o3;
        obase[d * 5 + 4] = o4;
    }
}

extern "C" void kernel_launch(void* const* d_in, const int* in_sizes, int n_in,
                              void* d_out, int out_size, void* d_ws, size_t ws_size,
                              hipStream_t stream) {
    (void)in_sizes; (void)n_in; (void)out_size; (void)ws_size;
    const float* loc  = (const float*)d_in[0];
    const float* conf = (const float*)d_in[1];
    const float* dbox = (const float*)d_in[2];
    float* out   = (float*)d_out;
    float* probs = (float*)d_ws;                                            // 89,415,680 B
    float* boxes = (float*)((char*)d_ws + (size_t)BATCH * 20 * N_ANCH * 4); // +17,883,136 B

    prep_kernel<<<(BATCH * N_ANCH) / 256, 256, 0, stream>>>(loc, conf, dbox, probs, boxes);
    sel_kernel<<<BATCH * NCLS, 256, 0, stream>>>(probs, boxes, probs);
    nms_kernel<<<BATCH * NCLS, 256, 0, stream>>>(probs, out);
}

// Round 27
// 210.882 us; speedup vs baseline: 1.3170x; 1.0002x over previous
//
#include <hip/hip_runtime.h>

#define N_ANCH 8732
#define NCLS   21
#define BATCH  128
#define TOPK   200
#define CONF_T 0.01f
#define HSIZE  1024        // logical buckets; populated range [0, 861]
#define CAND_MAX 1024
#define NQ4    2183        // 8732 / 4 exactly

// Exact div-free NMS threshold: RN(inter/denom) > 0.45f  <=>  inter > MD*denom
// (MD = midpoint(0.45f, nextafterf(0.45f)); tie rounds to even = 0.45f).
#define MD 0x1.CCCCCDp-2

// XLA:CPU GenerateVF32Exp (classic Cephes) compiled with AllowFPOpFusion=Fast.
__device__ __forceinline__ float exp_np(float x) {
    const float fx = floorf(__fmaf_rn(x, 1.442695040888963f, 0.5f));
    float t = __fmaf_rn(fx, -0.693359375f, x);
    t = __fmaf_rn(fx, 2.12194440e-4f, t);
    const float z = __fmul_rn(t, t);
    float y = 1.9875691500e-4f;
    y = __fmaf_rn(y, t, 1.3981999507e-3f);
    y = __fmaf_rn(y, t, 8.3334519073e-3f);
    y = __fmaf_rn(y, t, 4.1665795894e-2f);
    y = __fmaf_rn(y, t, 1.6666665459e-1f);
    y = __fmaf_rn(y, t, 5.0000001201e-1f);
    y = __fmaf_rn(y, z, t);
    y = __fadd_rn(y, 1.0f);
    return ldexpf(y, (int)fx);
}

// ---------------------------------------------------------------------------
// Kernel A (verified r18): VF=16 masked-tail vectorized reduce softmax +
// FMA-fused decode. probs transposed [b][c-1][n]; boxes [b][n][4].
// ---------------------------------------------------------------------------
__global__ __launch_bounds__(256) void prep_kernel(
    const float* __restrict__ loc, const float* __restrict__ conf,
    const float* __restrict__ dbox, float* __restrict__ probs,
    float* __restrict__ boxes)
{
    __shared__ float srow[256 * NCLS];
    const int block_row0 = blockIdx.x * 256;
    const float* cbase = conf + (size_t)block_row0 * NCLS;
    for (int i = threadIdx.x; i < 256 * NCLS; i += 256) srow[i] = cbase[i];
    __syncthreads();

    const int row = block_row0 + threadIdx.x;      // grid exact: 4366*256
    const int b = row / N_ANCH;
    const int n = row - b * N_ANCH;

    float e[NCLS];
    float m = srow[threadIdx.x * NCLS];
#pragma unroll
    for (int c = 1; c < NCLS; ++c) m = fmaxf(m, srow[threadIdx.x * NCLS + c]);
#pragma unroll
    for (int c = 0; c < NCLS; ++c)
        e[c] = exp_np(__fsub_rn(srow[threadIdx.x * NCLS + c], m));

    // VF=16 masked-tail reduce (verified r18)
    float acc[16];
#pragma unroll
    for (int j = 0; j < 16; ++j) acc[j] = e[j];
#pragma unroll
    for (int j = 0; j < 5; ++j) acc[j] = __fadd_rn(acc[j], e[16 + j]);
    float u[8];
#pragma unroll
    for (int j = 0; j < 8; ++j) u[j] = __fadd_rn(acc[j], acc[j + 8]);
    const float v0 = __fadd_rn(u[0], u[4]), v1 = __fadd_rn(u[1], u[5]);
    const float v2 = __fadd_rn(u[2], u[6]), v3 = __fadd_rn(u[3], u[7]);
    const float w0 = __fadd_rn(v0, v2), w1 = __fadd_rn(v1, v3);
    const float s  = __fadd_rn(w0, w1);

#pragma unroll
    for (int c = 1; c < NCLS; ++c)
        probs[((size_t)b * 20 + (c - 1)) * N_ANCH + n] = __fdiv_rn(e[c], s);

    const float4 l = *(const float4*)(loc + (size_t)row * 4);
    const float4 d = *(const float4*)(dbox + (size_t)n * 4);
    const float cx = __fmaf_rn(__fmul_rn(l.x, 0.1f), d.z, d.x);
    const float cy = __fmaf_rn(__fmul_rn(l.y, 0.1f), d.w, d.y);
    const float w  = __fmul_rn(d.z, exp_np(__fmul_rn(l.z, 0.2f)));
    const float h  = __fmul_rn(d.w, exp_np(__fmul_rn(l.w, 0.2f)));
    const float x1 = __fmaf_rn(w, -0.5f, cx);
    const float y1 = __fmaf_rn(h, -0.5f, cy);
    float4 o; o.x = x1; o.y = y1; o.z = __fadd_rn(x1, w); o.w = __fadd_rn(y1, h);
    *(float4*)(boxes + (size_t)row * 4) = o;
}

// ---------------------------------------------------------------------------
// Kernel B (fused): histogram top-200 + rank-sort + bitmask NMS + compaction,
// all in one block per task. LDS aliased: bxs overlays hist2 (dead after
// selection), rows overlays cand (dead after rank-select). All decision code
// byte-identical to the verified r26 paths.
// ---------------------------------------------------------------------------
__global__ __launch_bounds__(256) void sel_nms_kernel(
    const float* __restrict__ probs, const float* __restrict__ boxes,
    float* __restrict__ out)
{
    const int task = blockIdx.x;                  // b*21 + c
    const int b = task / NCLS;
    const int c = task - b * NCLS;
    const int tid = threadIdx.x;
    float* obase = out + (size_t)task * (TOPK * 5);

    if (c == 0) {
        for (int i = tid; i < TOPK * 5; i += 256) obase[i] = 0.f;
        return;
    }
    const float* prow = probs + ((size_t)b * 20 + (c - 1)) * N_ANCH;

    __shared__ __align__(16) char poolA[HSIZE * 2 * 4];   // hist2 -> bxs
    __shared__ __align__(16) char poolB[CAND_MAX * 8];    // cand  -> rows
    int* hist2 = (int*)poolA;                              // [HSIZE*2]
    float* bxs = (float*)poolA;                            // [TOPK*5] (4000 B)
    unsigned long long* cand = (unsigned long long*)poolB; // [CAND_MAX]
    unsigned long long (*rows)[4] = (unsigned long long (*)[4])poolB; // [TOPK][4]

    __shared__ int wsum[4];
    __shared__ int selB;
    __shared__ int cnts[2];
    __shared__ unsigned ck[TOPK];
    __shared__ int  cn[TOPK];
    __shared__ unsigned sk[TOPK];
    __shared__ int  sn_[TOPK];
    __shared__ unsigned long long Ksh[4];

    const int wid = tid >> 6, lane = tid & 63;
    const int par = wid & 1;

    // ==== selection (verified) =============================================
    for (int i = tid; i < HSIZE * 2; i += 256) hist2[i] = 0;
    __syncthreads();
    for (int idx = tid; idx < NQ4; idx += 256) {
        const float4 v = *(const float4*)(prow + idx * 4);
        if (v.x > CONF_T) atomicAdd(&hist2[(int)((__float_as_uint(v.x) >> 16) - 0x3C23u) * 2 + par], 1);
        if (v.y > CONF_T) atomicAdd(&hist2[(int)((__float_as_uint(v.y) >> 16) - 0x3C23u) * 2 + par], 1);
        if (v.z > CONF_T) atomicAdd(&hist2[(int)((__float_as_uint(v.z) >> 16) - 0x3C23u) * 2 + par], 1);
        if (v.w > CONF_T) atomicAdd(&hist2[(int)((__float_as_uint(v.w) >> 16) - 0x3C23u) * 2 + par], 1);
    }
    __syncthreads();

    const int hbase = HSIZE - 4 * (tid + 1);
    int hb[4];
#pragma unroll
    for (int j = 0; j < 4; ++j) hb[j] = hist2[(hbase + j) * 2] + hist2[(hbase + j) * 2 + 1];
    const int part = hb[0] + hb[1] + hb[2] + hb[3];

    int incl = part;
#pragma unroll
    for (int off = 1; off < 64; off <<= 1) {
        const int v = __shfl_up(incl, off);
        if (lane >= off) incl += v;
    }
    if (lane == 63) wsum[wid] = incl;
    __syncthreads();
    int pre = 0;
    for (int w = 0; w < wid; ++w) pre += wsum[w];
    const int excl  = pre + incl - part;
    const int total = wsum[0] + wsum[1] + wsum[2] + wsum[3];
    if (tid == 0 && total < TOPK) selB = -1;
    if (excl < TOPK && excl + part >= TOPK) {
        int cacc = excl;
        for (int j = 3; j >= 0; --j) {
            if (cacc + hb[j] >= TOPK) { selB = hbase + j; break; }
            cacc += hb[j];
        }
    }
    if (tid == 0) { cnts[0] = 0; cnts[1] = 0; }
    __syncthreads();
    const int B = selB;

    for (int idx = tid; idx < NQ4; idx += 256) {
        const float4 v = *(const float4*)(prow + idx * 4);
        const float vv[4] = {v.x, v.y, v.z, v.w};
#pragma unroll
        for (int q = 0; q < 4; ++q) {
            const float s = vv[q];
            if (s > CONF_T) {
                const unsigned kk = __float_as_uint(s);
                const int bkt = (int)((kk >> 16) - 0x3C23u);
                if (bkt > B) {
                    const int p = atomicAdd(&cnts[0], 1);
                    ck[p] = kk; cn[p] = idx * 4 + q;
                } else if (bkt == B) {
                    const int qq = atomicAdd(&cnts[1], 1);
                    if (qq < CAND_MAX)
                        cand[qq] = ((unsigned long long)kk << 32) | (unsigned)(~(idx * 4 + q));
                }
            }
        }
    }
    __syncthreads();
    const int ndef  = cnts[0];
    const int slots = TOPK - ndef;
    int cc = cnts[1]; if (cc > CAND_MAX) cc = CAND_MAX;

    if (cc <= slots) {
        for (int i = tid; i < cc; i += 256) {
            const unsigned long long mine = cand[i];
            const int p = atomicAdd(&cnts[0], 1);
            ck[p] = (unsigned)(mine >> 32);
            cn[p] = (int)(~(unsigned)mine);
        }
        __syncthreads();
    } else {
        // level-2 refinement on key bits 8..15 (verified r26)
        for (int i = tid; i < 256; i += 256) hist2[i] = 0;
        __syncthreads();
        for (int i = tid; i < cc; i += 256)
            atomicAdd(&hist2[(int)((cand[i] >> 40) & 0xFFull)], 1);
        __syncthreads();
        const int sb = 255 - tid;
        const int part2 = hist2[sb];
        int incl2 = part2;
#pragma unroll
        for (int off = 1; off < 64; off <<= 1) {
            const int v = __shfl_up(incl2, off);
            if (lane >= off) incl2 += v;
        }
        if (lane == 63) wsum[wid] = incl2;
        __syncthreads();
        int pre2 = 0;
        for (int w = 0; w < wid; ++w) pre2 += wsum[w];
        const int excl2 = pre2 + incl2 - part2;
        if (excl2 < slots && excl2 + part2 >= slots) selB = sb;
        __syncthreads();
        const int B2 = selB;
        for (int i = tid; i < cc; i += 256) {
            const unsigned long long mine = cand[i];
            if ((int)((mine >> 40) & 0xFFull) > B2) {
                const int p = atomicAdd(&cnts[0], 1);
                ck[p] = (unsigned)(mine >> 32);
                cn[p] = (int)(~(unsigned)mine);
            }
        }
        __syncthreads();
        const int slots2 = TOPK - cnts[0];
        for (int i = tid; i < cc; i += 256) {
            const unsigned long long mine = cand[i];
            if ((int)((mine >> 40) & 0xFFull) == B2) {
                int rank = 0;
                for (int j = 0; j < cc; ++j) {
                    const unsigned long long oth = cand[j];
                    rank += (((int)((oth >> 40) & 0xFFull) == B2) && oth > mine) ? 1 : 0;
                }
                if (rank < slots2) {
                    const int p = atomicAdd(&cnts[0], 1);
                    ck[p] = (unsigned)(mine >> 32);
                    cn[p] = (int)(~(unsigned)mine);
                }
            }
        }
        __syncthreads();
    }
    const int cnt_arr = cnts[0];

    // ==== rank-sort (verified) =============================================
    if (tid < TOPK) { sk[tid] = 0u; sn_[tid] = -1; }
    __syncthreads();
    if (tid < cnt_arr) {
        const unsigned mk = ck[tid];
        const int mn = cn[tid];
        int rank = 0;
        for (int j = 0; j < cnt_arr; ++j) {
            const unsigned kj = ck[j];
            rank += (kj > mk || (kj == mk && cn[j] < mn)) ? 1 : 0;
        }
        sk[rank] = mk; sn_[rank] = mn;
    }
    __syncthreads();          // hist2 dead; cand dead — pools reusable

    // ==== gather boxes into LDS (bxs aliases poolA) ========================
    if (tid < TOPK) {
        const int n = sn_[tid];
        float scv = 0.f;
        float4 bx = make_float4(0.f, 0.f, 0.f, 0.f);
        if (n >= 0) {
            scv = __uint_as_float(sk[tid]);
            bx = *(const float4*)(boxes + ((size_t)b * N_ANCH + n) * 4);
        }
        bxs[tid * 5 + 0] = scv;
        bxs[tid * 5 + 1] = bx.x; bxs[tid * 5 + 2] = bx.y;
        bxs[tid * 5 + 3] = bx.z; bxs[tid * 5 + 4] = bx.w;
    }
    __syncthreads();

    // ==== bitmask NMS phase 1 (verified r26, rows aliases poolB) ===========
    float jx1[4], jy1[4], jx2[4], jy2[4], jar[4];
    int jval[4];
#pragma unroll
    for (int s = 0; s < 4; ++s) {
        const int j = s * 64 + lane;
        float a = 0.f, p1 = 0.f, p2 = 0.f, p3 = 0.f, p4 = 0.f;
        if (j < TOPK) {
            a = bxs[j * 5 + 0];
            p1 = bxs[j * 5 + 1]; p2 = bxs[j * 5 + 2];
            p3 = bxs[j * 5 + 3]; p4 = bxs[j * 5 + 4];
        }
        jx1[s] = p1; jy1[s] = p2; jx2[s] = p3; jy2[s] = p4;
        jar[s] = __fmul_rn(__fsub_rn(p3, p1), __fsub_rn(p4, p2));
        jval[s] = (a > CONF_T) ? 1 : 0;
    }
    if (wid == 0) {
#pragma unroll
        for (int s = 0; s < 4; ++s) {
            const unsigned long long m = __ballot(jval[s] != 0);
            if (lane == 0) Ksh[s] = m;
        }
    }

    for (int i = wid; i < TOPK; i += 4) {
        const int smin = i >> 6;
        const float ix1 = bxs[i * 5 + 1], iy1 = bxs[i * 5 + 2];
        const float ix2 = bxs[i * 5 + 3], iy2 = bxs[i * 5 + 4];
        (void)iy1;
#pragma unroll
        for (int s = 0; s < 4; ++s) {
            if (s < smin) {
                if (lane == 0) rows[i][s] = 0ull;
            } else {
                const int j = s * 64 + lane;
                const float w = fmaxf(0.f, __fsub_rn(fminf(jx2[s], ix2), fmaxf(jx1[s], ix1)));
                const float h = fmaxf(0.f, __fsub_rn(fminf(jy2[s], bxs[i * 5 + 4]), fmaxf(jy1[s], bxs[i * 5 + 2])));
                const float inter = __fmul_rn(w, h);
                const float ia = __fmul_rn(__fsub_rn(ix2, ix1), __fsub_rn(bxs[i * 5 + 4], bxs[i * 5 + 2]));
                const float denom = __fadd_rn(__fsub_rn(jar[s], inter), ia);
                const bool bit = (j < TOPK) && (j > i) &&
                                 ((double)inter > MD * (double)denom);
                const unsigned long long m = __ballot(bit);
                if (lane == 0) rows[i][s] = m;
            }
        }
    }
    __syncthreads();

    // ==== phase 2: serial resolution on wave 0 (verified r26) ==============
    if (wid == 0) {
        unsigned long long K0 = Ksh[0], K1 = Ksh[1], K2 = Ksh[2], K3 = Ksh[3];
#pragma unroll
        for (int w4 = 0; w4 < 4; ++w4) {
            const int lim = (w4 < 3) ? 64 : (TOPK - 192);
            for (int o = 0; o < lim; ++o) {
                const int i = w4 * 64 + o;
                const ulonglong2 ra = *(const ulonglong2*)&rows[i][0];
                const ulonglong2 rb = *(const ulonglong2*)&rows[i][2];
                if ((ra.x | ra.y | rb.x | rb.y) == 0ull) continue;
                unsigned long long live;
                if (w4 == 0) live = (K0 >> o) & 1ull;
                else if (w4 == 1) live = (K1 >> o) & 1ull;
                else if (w4 == 2) live = (K2 >> o) & 1ull;
                else live = (K3 >> o) & 1ull;
                const unsigned long long msel = 0ull - live;
                K0 &= ~(ra.x & msel);
                K1 &= ~(ra.y & msel);
                K2 &= ~(rb.x & msel);
                K3 &= ~(rb.y & msel);
            }
        }
        if (lane == 0) { Ksh[0] = K0; Ksh[1] = K1; Ksh[2] = K2; Ksh[3] = K3; }
    }
    __syncthreads();

    // ==== phase 3: dest-driven stable compaction (verified r24/r26) ========
    if (tid < TOPK) {
        const unsigned long long K0 = Ksh[0], K1 = Ksh[1], K2 = Ksh[2], K3 = Ksh[3];
        const int d = tid;
        const int c0 = (int)__popcll(K0), c1 = (int)__popcll(K1),
                  c2 = (int)__popcll(K2), c3 = (int)__popcll(K3);
        const int totalk = c0 + c1 + c2 + c3;
        float o0 = 0.f, o1 = 0.f, o2 = 0.f, o3 = 0.f, o4 = 0.f;
        if (d < totalk) {
            int r = d;
            unsigned long long x;
            int wbase;
            if (r < c0)               { x = K0; wbase = 0;   }
            else if (r < c0 + c1)     { x = K1; wbase = 64;  r -= c0; }
            else if (r < c0 + c1 + c2){ x = K2; wbase = 128; r -= c0 + c1; }
            else                      { x = K3; wbase = 192; r -= c0 + c1 + c2; }
            for (int t = 0; t < r; ++t) x &= x - 1ull;
            const int p = wbase + (__ffsll((unsigned long long)x) - 1);
            o0 = bxs[p * 5 + 0]; o1 = bxs[p * 5 + 1]; o2 = bxs[p * 5 + 2];
            o3 = bxs[p * 5 + 3]; o4 = bxs[p * 5 + 4];
        }
        obase[d * 5 + 0] = o0;
        obase[d * 5 + 1] = o1;
        obase[d * 5 + 2] = o2;
        obase[d * 5 + 3] = o3;
        obase[d * 5 + 4] = o4;
    }
}

extern "C" void kernel_launch(void* const* d_in, const int* in_sizes, int n_in,
                              void* d_out, int out_size, void* d_ws, size_t ws_size,
                              hipStream_t stream) {
    (void)in_sizes; (void)n_in; (void)out_size; (void)ws_size;
    const float* loc  = (const float*)d_in[0];
    const float* conf = (const float*)d_in[1];
    const float* dbox = (const float*)d_in[2];
    float* out   = (float*)d_out;
    float* probs = (float*)d_ws;                                            // 89,415,680 B
    float* boxes = (float*)((char*)d_ws + (size_t)BATCH * 20 * N_ANCH * 4); // +17,883,136 B

    prep_kernel<<<(BATCH * N_ANCH) / 256, 256, 0, stream>>>(loc, conf, dbox, probs, boxes);
    sel_nms_kernel<<<BATCH * NCLS, 256, 0, stream>>>(probs, boxes, out);
}

// Round 28
// 198.033 us; speedup vs baseline: 1.4025x; 1.0649x over previous
//
#include <hip/hip_runtime.h>

#define N_ANCH 8732
#define NCLS   21
#define BATCH  128
#define TOPK   200
#define CONF_T 0.01f
#define HSIZE  1024        // logical buckets; populated range [0, 861]
#define CAND_MAX 1024
#define NQ4    2183        // 8732 / 4 exactly

// Exact div-free NMS threshold: RN(inter/denom) > 0.45f  <=>  inter > MD*denom
#define MD 0x1.CCCCCDp-2

// XLA:CPU GenerateVF32Exp (classic Cephes) compiled with AllowFPOpFusion=Fast.
__device__ __forceinline__ float exp_np(float x) {
    const float fx = floorf(__fmaf_rn(x, 1.442695040888963f, 0.5f));
    float t = __fmaf_rn(fx, -0.693359375f, x);
    t = __fmaf_rn(fx, 2.12194440e-4f, t);
    const float z = __fmul_rn(t, t);
    float y = 1.9875691500e-4f;
    y = __fmaf_rn(y, t, 1.3981999507e-3f);
    y = __fmaf_rn(y, t, 8.3334519073e-3f);
    y = __fmaf_rn(y, t, 4.1665795894e-2f);
    y = __fmaf_rn(y, t, 1.6666665459e-1f);
    y = __fmaf_rn(y, t, 5.0000001201e-1f);
    y = __fmaf_rn(y, z, t);
    y = __fadd_rn(y, 1.0f);
    return ldexpf(y, (int)fx);
}

// ---------------------------------------------------------------------------
// Kernel A (verified r18): VF=16 masked-tail vectorized reduce softmax +
// FMA-fused decode. probs transposed [b][c-1][n]; boxes [b][n][4].
// ---------------------------------------------------------------------------
__global__ __launch_bounds__(256) void prep_kernel(
    const float* __restrict__ loc, const float* __restrict__ conf,
    const float* __restrict__ dbox, float* __restrict__ probs,
    float* __restrict__ boxes)
{
    __shared__ float srow[256 * NCLS];
    const int block_row0 = blockIdx.x * 256;
    const float* cbase = conf + (size_t)block_row0 * NCLS;
    for (int i = threadIdx.x; i < 256 * NCLS; i += 256) srow[i] = cbase[i];
    __syncthreads();

    const int row = block_row0 + threadIdx.x;      // grid exact: 4366*256
    const int b = row / N_ANCH;
    const int n = row - b * N_ANCH;

    float e[NCLS];
    float m = srow[threadIdx.x * NCLS];
#pragma unroll
    for (int c = 1; c < NCLS; ++c) m = fmaxf(m, srow[threadIdx.x * NCLS + c]);
#pragma unroll
    for (int c = 0; c < NCLS; ++c)
        e[c] = exp_np(__fsub_rn(srow[threadIdx.x * NCLS + c], m));

    // VF=16 masked-tail reduce (verified r18)
    float acc[16];
#pragma unroll
    for (int j = 0; j < 16; ++j) acc[j] = e[j];
#pragma unroll
    for (int j = 0; j < 5; ++j) acc[j] = __fadd_rn(acc[j], e[16 + j]);
    float u[8];
#pragma unroll
    for (int j = 0; j < 8; ++j) u[j] = __fadd_rn(acc[j], acc[j + 8]);
    const float v0 = __fadd_rn(u[0], u[4]), v1 = __fadd_rn(u[1], u[5]);
    const float v2 = __fadd_rn(u[2], u[6]), v3 = __fadd_rn(u[3], u[7]);
    const float w0 = __fadd_rn(v0, v2), w1 = __fadd_rn(v1, v3);
    const float s  = __fadd_rn(w0, w1);

#pragma unroll
    for (int c = 1; c < NCLS; ++c)
        probs[((size_t)b * 20 + (c - 1)) * N_ANCH + n] = __fdiv_rn(e[c], s);

    const float4 l = *(const float4*)(loc + (size_t)row * 4);
    const float4 d = *(const float4*)(dbox + (size_t)n * 4);
    const float cx = __fmaf_rn(__fmul_rn(l.x, 0.1f), d.z, d.x);
    const float cy = __fmaf_rn(__fmul_rn(l.y, 0.1f), d.w, d.y);
    const float w  = __fmul_rn(d.z, exp_np(__fmul_rn(l.z, 0.2f)));
    const float h  = __fmul_rn(d.w, exp_np(__fmul_rn(l.w, 0.2f)));
    const float x1 = __fmaf_rn(w, -0.5f, cx);
    const float y1 = __fmaf_rn(h, -0.5f, cy);
    float4 o; o.x = x1; o.y = y1; o.z = __fadd_rn(x1, w); o.w = __fadd_rn(y1, h);
    *(float4*)(boxes + (size_t)row * 4) = o;
}

// ---------------------------------------------------------------------------
// Kernel B (fused, lean): histogram top-200 + rank-sort + bitmask NMS +
// compaction. LDS aliased: bxs overlays hist (dead), rows overlays cand
// (dead). All decision math bit-identical to verified r26/r27 paths.
// ---------------------------------------------------------------------------
__global__ __launch_bounds__(256) void sel_nms_kernel(
    const float* __restrict__ probs, const float* __restrict__ boxes,
    float* __restrict__ out)
{
    const int task = blockIdx.x;                  // b*21 + c
    const int b = task / NCLS;
    const int c = task - b * NCLS;
    const int tid = threadIdx.x;
    float* obase = out + (size_t)task * (TOPK * 5);

    if (c == 0) {
        for (int i = tid; i < TOPK * 5; i += 256) obase[i] = 0.f;
        return;
    }
    const float* prow = probs + ((size_t)b * 20 + (c - 1)) * N_ANCH;

    __shared__ __align__(16) char poolA[TOPK * 8 * 4];    // hist (4KB) -> bxs (6.4KB)
    __shared__ __align__(16) char poolB[CAND_MAX * 8];    // cand (8KB) -> rows (6.4KB)
    int* hist = (int*)poolA;                               // [HSIZE]
    float* bxs = (float*)poolA;                            // [TOPK*8]
    unsigned long long* cand = (unsigned long long*)poolB; // [CAND_MAX]
    unsigned long long (*rows)[4] = (unsigned long long (*)[4])poolB; // [TOPK][4]

    __shared__ int wsum[4];
    __shared__ int selB;
    __shared__ int cnts[2];
    __shared__ unsigned ck[TOPK];
    __shared__ int  cn[TOPK];
    __shared__ unsigned sk[TOPK];
    __shared__ int  sn_[TOPK];
    __shared__ unsigned long long Ksh[4];

    const int wid = tid >> 6, lane = tid & 63;

    // ==== selection: pass 1 histogram (verified semantics) =================
    for (int i = tid; i < HSIZE; i += 256) hist[i] = 0;
    __syncthreads();
    for (int idx = tid; idx < NQ4; idx += 256) {
        const float4 v = *(const float4*)(prow + idx * 4);
        if (v.x > CONF_T) atomicAdd(&hist[(int)((__float_as_uint(v.x) >> 16) - 0x3C23u)], 1);
        if (v.y > CONF_T) atomicAdd(&hist[(int)((__float_as_uint(v.y) >> 16) - 0x3C23u)], 1);
        if (v.z > CONF_T) atomicAdd(&hist[(int)((__float_as_uint(v.z) >> 16) - 0x3C23u)], 1);
        if (v.w > CONF_T) atomicAdd(&hist[(int)((__float_as_uint(v.w) >> 16) - 0x3C23u)], 1);
    }
    __syncthreads();

    // ==== boundary bucket B ================================================
    const int hbase = HSIZE - 4 * (tid + 1);
    int hb[4];
#pragma unroll
    for (int j = 0; j < 4; ++j) hb[j] = hist[hbase + j];
    const int part = hb[0] + hb[1] + hb[2] + hb[3];

    int incl = part;
#pragma unroll
    for (int off = 1; off < 64; off <<= 1) {
        const int v = __shfl_up(incl, off);
        if (lane >= off) incl += v;
    }
    if (lane == 63) wsum[wid] = incl;
    __syncthreads();
    int pre = 0;
    for (int w = 0; w < wid; ++w) pre += wsum[w];
    const int excl  = pre + incl - part;
    const int total = wsum[0] + wsum[1] + wsum[2] + wsum[3];
    if (tid == 0 && total < TOPK) selB = -1;
    if (excl < TOPK && excl + part >= TOPK) {
        int cacc = excl;
        for (int j = 3; j >= 0; --j) {
            if (cacc + hb[j] >= TOPK) { selB = hbase + j; break; }
            cacc += hb[j];
        }
    }
    if (tid == 0) { cnts[0] = 0; cnts[1] = 0; }
    __syncthreads();
    const int B = selB;

    // ==== pass 2: compact definites; collect boundary candidates ===========
    for (int idx = tid; idx < NQ4; idx += 256) {
        const float4 v = *(const float4*)(prow + idx * 4);
        const float vv[4] = {v.x, v.y, v.z, v.w};
#pragma unroll
        for (int q = 0; q < 4; ++q) {
            const float s = vv[q];
            if (s > CONF_T) {
                const unsigned kk = __float_as_uint(s);
                const int bkt = (int)((kk >> 16) - 0x3C23u);
                if (bkt > B) {
                    const int p = atomicAdd(&cnts[0], 1);
                    ck[p] = kk; cn[p] = idx * 4 + q;
                } else if (bkt == B) {
                    const int qq = atomicAdd(&cnts[1], 1);
                    if (qq < CAND_MAX)
                        cand[qq] = ((unsigned long long)kk << 32) | (unsigned)(~(idx * 4 + q));
                }
            }
        }
    }
    __syncthreads();
    const int ndef  = cnts[0];
    const int slots = TOPK - ndef;
    int cc = cnts[1]; if (cc > CAND_MAX) cc = CAND_MAX;

    if (cc <= slots) {
        for (int i = tid; i < cc; i += 256) {
            const unsigned long long mine = cand[i];
            const int p = atomicAdd(&cnts[0], 1);
            ck[p] = (unsigned)(mine >> 32);
            cn[p] = (int)(~(unsigned)mine);
        }
        __syncthreads();
    } else {
        // level-2 refinement on key bits 8..15 (verified r26)
        for (int i = tid; i < 256; i += 256) hist[i] = 0;
        __syncthreads();
        for (int i = tid; i < cc; i += 256)
            atomicAdd(&hist[(int)((cand[i] >> 40) & 0xFFull)], 1);
        __syncthreads();
        const int sb = 255 - tid;
        const int part2 = hist[sb];
        int incl2 = part2;
#pragma unroll
        for (int off = 1; off < 64; off <<= 1) {
            const int v = __shfl_up(incl2, off);
            if (lane >= off) incl2 += v;
        }
        if (lane == 63) wsum[wid] = incl2;
        __syncthreads();
        int pre2 = 0;
        for (int w = 0; w < wid; ++w) pre2 += wsum[w];
        const int excl2 = pre2 + incl2 - part2;
        if (excl2 < slots && excl2 + part2 >= slots) selB = sb;
        __syncthreads();
        const int B2 = selB;
        for (int i = tid; i < cc; i += 256) {
            const unsigned long long mine = cand[i];
            if ((int)((mine >> 40) & 0xFFull) > B2) {
                const int p = atomicAdd(&cnts[0], 1);
                ck[p] = (unsigned)(mine >> 32);
                cn[p] = (int)(~(unsigned)mine);
            }
        }
        __syncthreads();
        const int slots2 = TOPK - cnts[0];
        for (int i = tid; i < cc; i += 256) {
            const unsigned long long mine = cand[i];
            if ((int)((mine >> 40) & 0xFFull) == B2) {
                int rank = 0;
                for (int j = 0; j < cc; ++j) {
                    const unsigned long long oth = cand[j];
                    rank += (((int)((oth >> 40) & 0xFFull) == B2) && oth > mine) ? 1 : 0;
                }
                if (rank < slots2) {
                    const int p = atomicAdd(&cnts[0], 1);
                    ck[p] = (unsigned)(mine >> 32);
                    cn[p] = (int)(~(unsigned)mine);
                }
            }
        }
        __syncthreads();
    }
    const int cnt_arr = cnts[0];

    // ==== rank-sort (verified) =============================================
    if (tid < TOPK) { sk[tid] = 0u; sn_[tid] = -1; }
    __syncthreads();
    if (tid < cnt_arr) {
        const unsigned mk = ck[tid];
        const int mn = cn[tid];
        int rank = 0;
        for (int j = 0; j < cnt_arr; ++j) {
            const unsigned kj = ck[j];
            rank += (kj > mk || (kj == mk && cn[j] < mn)) ? 1 : 0;
        }
        sk[rank] = mk; sn_[rank] = mn;
    }
    __syncthreads();          // hist dead; cand dead after next phase begins

    // ==== gather boxes stride-8 {x1,y1,x2,y2,score,area} (bxs -> poolA) ====
    if (tid < TOPK) {
        const int n = sn_[tid];
        float scv = 0.f;
        float4 bx = make_float4(0.f, 0.f, 0.f, 0.f);
        if (n >= 0) {
            scv = __uint_as_float(sk[tid]);
            bx = *(const float4*)(boxes + ((size_t)b * N_ANCH + n) * 4);
        }
        *(float4*)&bxs[tid * 8] = bx;
        bxs[tid * 8 + 4] = scv;
        bxs[tid * 8 + 5] = __fmul_rn(__fsub_rn(bx.z, bx.x), __fsub_rn(bx.w, bx.y));
    }
    __syncthreads();

    // ==== pre-zero rows (aliases poolB; cand dead) =========================
    for (int k = tid; k < TOPK * 4; k += 256) ((unsigned long long*)rows)[k] = 0ull;

    // per-lane j-boxes (slot s: j = s*64+lane)
    float jx1[4], jy1[4], jx2[4], jy2[4], jar[4];
    int jval[4];
#pragma unroll
    for (int s = 0; s < 4; ++s) {
        const int j = s * 64 + lane;
        float4 bx = make_float4(0.f, 0.f, 0.f, 0.f);
        float a = 0.f, ar = 0.f;
        if (j < TOPK) {
            bx = *(const float4*)&bxs[j * 8];
            a  = bxs[j * 8 + 4];
            ar = bxs[j * 8 + 5];
        }
        jx1[s] = bx.x; jy1[s] = bx.y; jx2[s] = bx.z; jy2[s] = bx.w;
        jar[s] = ar;
        jval[s] = (a > CONF_T) ? 1 : 0;
    }
    if (wid == 0) {
#pragma unroll
        for (int s = 0; s < 4; ++s) {
            const unsigned long long m = __ballot(jval[s] != 0);
            if (lane == 0) Ksh[s] = m;
        }
    }
    __syncthreads();   // rows zero-init visible to all

    // ==== phase 1: suppression rows, hoisted i-box, no per-lane predicates =
    for (int i = wid; i < TOPK; i += 4) {
        const int smin = i >> 6;
        const float4 ib = *(const float4*)&bxs[i * 8];
        const float ia  = bxs[i * 8 + 5];
#pragma unroll
        for (int s = 0; s < 4; ++s) {
            if (s >= smin) {                       // wave-uniform branch
                const float w = fmaxf(0.f, __fsub_rn(fminf(jx2[s], ib.z), fmaxf(jx1[s], ib.x)));
                const float h = fmaxf(0.f, __fsub_rn(fminf(jy2[s], ib.w), fmaxf(jy1[s], ib.y)));
                const float inter = __fmul_rn(w, h);
                const float denom = __fadd_rn(__fsub_rn(jar[s], inter), ia);
                // zero-box pairs give inter=0 -> bit false; j<=i cleared below
                unsigned long long m = __ballot((double)inter > MD * (double)denom);
                if (lane == 0) {
                    if (s == smin) m &= ~((2ull << (i & 63)) - 1ull);  // clear j<=i
                    rows[i][s] = m;
                }
            }
        }
    }
    __syncthreads();

    // ==== phase 2: serial resolution on wave 0 (verified r26) ==============
    if (wid == 0) {
        unsigned long long K0 = Ksh[0], K1 = Ksh[1], K2 = Ksh[2], K3 = Ksh[3];
#pragma unroll
        for (int w4 = 0; w4 < 4; ++w4) {
            const int lim = (w4 < 3) ? 64 : (TOPK - 192);
            for (int o = 0; o < lim; ++o) {
                const int i = w4 * 64 + o;
                const ulonglong2 ra = *(const ulonglong2*)&rows[i][0];
                const ulonglong2 rb = *(const ulonglong2*)&rows[i][2];
                if ((ra.x | ra.y | rb.x | rb.y) == 0ull) continue;
                unsigned long long live;
                if (w4 == 0) live = (K0 >> o) & 1ull;
                else if (w4 == 1) live = (K1 >> o) & 1ull;
                else if (w4 == 2) live = (K2 >> o) & 1ull;
                else live = (K3 >> o) & 1ull;
                const unsigned long long msel = 0ull - live;
                K0 &= ~(ra.x & msel);
                K1 &= ~(ra.y & msel);
                K2 &= ~(rb.x & msel);
                K3 &= ~(rb.y & msel);
            }
        }
        if (lane == 0) { Ksh[0] = K0; Ksh[1] = K1; Ksh[2] = K2; Ksh[3] = K3; }
    }
    __syncthreads();

    // ==== phase 3: dest-driven stable compaction (verified) ================
    if (tid < TOPK) {
        const unsigned long long K0 = Ksh[0], K1 = Ksh[1], K2 = Ksh[2], K3 = Ksh[3];
        const int d = tid;
        const int c0 = (int)__popcll(K0), c1 = (int)__popcll(K1),
                  c2 = (int)__popcll(K2), c3 = (int)__popcll(K3);
        const int totalk = c0 + c1 + c2 + c3;
        float o0 = 0.f, o1 = 0.f, o2 = 0.f, o3 = 0.f, o4 = 0.f;
        if (d < totalk) {
            int r = d;
            unsigned long long x;
            int wbase;
            if (r < c0)               { x = K0; wbase = 0;   }
            else if (r < c0 + c1)     { x = K1; wbase = 64;  r -= c0; }
            else if (r < c0 + c1 + c2){ x = K2; wbase = 128; r -= c0 + c1; }
            else                      { x = K3; wbase = 192; r -= c0 + c1 + c2; }
            for (int t = 0; t < r; ++t) x &= x - 1ull;
            const int p = wbase + (__ffsll((unsigned long long)x) - 1);
            o0 = bxs[p * 8 + 4];
            o1 = bxs[p * 8 + 0]; o2 = bxs[p * 8 + 1];
            o3 = bxs[p * 8 + 2]; o4 = bxs[p * 8 + 3];
        }
        obase[d * 5 + 0] = o0;
        obase[d * 5 + 1] = o1;
        obase[d * 5 + 2] = o2;
        obase[d * 5 + 3] = o3;
        obase[d * 5 + 4] = o4;
    }
}

extern "C" void kernel_launch(void* const* d_in, const int* in_sizes, int n_in,
                              void* d_out, int out_size, void* d_ws, size_t ws_size,
                              hipStream_t stream) {
    (void)in_sizes; (void)n_in; (void)out_size; (void)ws_size;
    const float* loc  = (const float*)d_in[0];
    const float* conf = (const float*)d_in[1];
    const float* dbox = (const float*)d_in[2];
    float* out   = (float*)d_out;
    float* probs = (float*)d_ws;                                            // 89,415,680 B
    float* boxes = (float*)((char*)d_ws + (size_t)BATCH * 20 * N_ANCH * 4); // +17,883,136 B

    prep_kernel<<<(BATCH * N_ANCH) / 256, 256, 0, stream>>>(loc, conf, dbox, probs, boxes);
    sel_nms_kernel<<<BATCH * NCLS, 256, 0, stream>>>(probs, boxes, out);
}